// Round 7
// baseline (744.578 us; speedup 1.0000x reference)
//
#include <hip/hip_runtime.h>
#include <hip/hip_bf16.h>

#define BTOK 8192
#define DDIM 1024
#define NEXP 8

typedef unsigned short u16;
typedef unsigned int u32;
typedef __attribute__((ext_vector_type(8))) short short8;
typedef __attribute__((ext_vector_type(4))) float f32x4;

constexpr int BM = 256, BN = 256, BK = 32;
constexpr int SLOTCAP = 3072;
constexpr int NT = DDIM / BK;          // 32 K-tiles

__device__ __forceinline__ u16 f2bf(float f){
  __hip_bfloat16 h = __float2bfloat16(f);
  return *reinterpret_cast<u16*>(&h);
}
__device__ __forceinline__ float bf2f(u16 v){
  return __uint_as_float(((u32)v) << 16);
}
__device__ __forceinline__ void gll16(const u16* gsrc, u16* ldst){
  __builtin_amdgcn_global_load_lds((const __attribute__((address_space(1))) void*)gsrc,
                                   (__attribute__((address_space(3))) void*)ldst,
                                   16, 0, 0);
}

// ---------------- cast x -> bf16 ----------------
__global__ __launch_bounds__(256) void cast_x_kernel(const float4* __restrict__ x4,
                                                     ushort4* __restrict__ xb4)
{
  const int i = blockIdx.x*256 + threadIdx.x;
  const float4 v = x4[i];
  xb4[i] = make_ushort4(f2bf(v.x), f2bf(v.y), f2bf(v.z), f2bf(v.w));
}

// ---------------- W' prep: W'T[n][d] hi/lo bf16, n<8 = Wg col, n>=8 = Wn col ----------------
__global__ __launch_bounds__(256) void wprep_kernel(
    const float* __restrict__ Wg, const float* __restrict__ Wn,
    u16* __restrict__ wpt)
{
  const int idx = blockIdx.x*256 + threadIdx.x;     // 16384 = 16 n x 1024 d
  const int n = idx >> 10, d = idx & 1023;
  const float v = (n < 8) ? Wg[d*8 + n] : Wn[d*8 + (n-8)];
  const u16 hi = f2bf(v);
  const u16 lo = f2bf(v - bf2f(hi));
  wpt[n*1024 + d]          = hi;
  wpt[16384 + n*1024 + d]  = lo;
}

// ---------------- gating score: h' = x @ W' via split-bf16 MFMA ----------------
// grid 256 x 128 threads (2 waves, 16 tokens each). W'T hi+lo resident in LDS.
__global__ __launch_bounds__(128) void score_kernel(
    const float* __restrict__ x, const u16* __restrict__ xb,
    const u16* __restrict__ wpt, float* __restrict__ hp)
{
  __shared__ __align__(16) u16 lw[2][16][1024];   // 64 KB
  const int tid = threadIdx.x;
  const int wave = tid >> 6, lane = tid & 63;

  // stage W'T hi/lo; XOR-swizzle 16B-chunk index by (n&7) to kill bank conflicts
  for (int it = 0; it < 32; ++it){
    const int cid = it*128 + tid;                 // 0..4095 (16B chunks)
    const int v = cid >> 11, rem = cid & 2047;
    const int n = rem >> 7, c = rem & 127;
    const short8 val = *reinterpret_cast<const short8*>(wpt + v*16384 + n*1024 + c*8);
    *reinterpret_cast<short8*>(&lw[v][n][(c ^ (n&7))*8]) = val;
  }
  __syncthreads();

  const int q = lane >> 4, l16 = lane & 15;
  const int t0 = blockIdx.x*32 + wave*16;
  const int rowA = t0 + l16;
  const u16*   xbp = xb + (size_t)rowA*DDIM + q*8;
  const float* xp  = x  + (size_t)rowA*DDIM + q*8;

  f32x4 acc0 = {0.f,0.f,0.f,0.f}, acc1 = acc0, acc2 = acc0;
  for (int kt = 0; kt < 32; ++kt){
    const short8 ah = *reinterpret_cast<const short8*>(xbp + kt*32);
    const float4 x0 = *reinterpret_cast<const float4*>(xp + kt*32);
    const float4 x1 = *reinterpret_cast<const float4*>(xp + kt*32 + 4);
    short8 al;
    al[0]=(short)f2bf(x0.x - bf2f((u16)ah[0])); al[1]=(short)f2bf(x0.y - bf2f((u16)ah[1]));
    al[2]=(short)f2bf(x0.z - bf2f((u16)ah[2])); al[3]=(short)f2bf(x0.w - bf2f((u16)ah[3]));
    al[4]=(short)f2bf(x1.x - bf2f((u16)ah[4])); al[5]=(short)f2bf(x1.y - bf2f((u16)ah[5]));
    al[6]=(short)f2bf(x1.z - bf2f((u16)ah[6])); al[7]=(short)f2bf(x1.w - bf2f((u16)ah[7]));
    const int bs = ((kt*4 + q) ^ (l16 & 7)) * 8;
    const short8 bh = *reinterpret_cast<const short8*>(&lw[0][l16][bs]);
    const short8 bl = *reinterpret_cast<const short8*>(&lw[1][l16][bs]);
    acc0 = __builtin_amdgcn_mfma_f32_16x16x32_bf16(ah, bh, acc0, 0, 0, 0);
    acc1 = __builtin_amdgcn_mfma_f32_16x16x32_bf16(al, bh, acc1, 0, 0, 0);
    acc2 = __builtin_amdgcn_mfma_f32_16x16x32_bf16(ah, bl, acc2, 0, 0, 0);
  }
  #pragma unroll
  for (int r = 0; r < 4; ++r)
    hp[(size_t)(t0 + q*4 + r)*16 + l16] = acc0[r] + acc1[r] + acc2[r];
}

// ---------------- gating select: noise + softplus + top-k + softmax + slot alloc ----------------
__global__ __launch_bounds__(256) void gating_select_kernel(
    const float* __restrict__ hp, const float* __restrict__ noise,
    const int* __restrict__ kp,
    float* __restrict__ gates, int* __restrict__ counts, int* __restrict__ lists,
    int* __restrict__ tokmap, int* __restrict__ ncnt)
{
  __shared__ int lcnt[NEXP];
  __shared__ int lbase[NEXP];
  const int tid = threadIdx.x;
  const int t   = blockIdx.x*256 + tid;
  if (tid < NEXP) lcnt[tid] = 0;
  __syncthreads();

  float hg[16];
  #pragma unroll
  for (int i = 0; i < 4; ++i){
    const float4 v = reinterpret_cast<const float4*>(hp + (size_t)t*16)[i];
    hg[i*4+0]=v.x; hg[i*4+1]=v.y; hg[i*4+2]=v.z; hg[i*4+3]=v.w;
  }
  float h[NEXP];
  #pragma unroll
  for (int e = 0; e < NEXP; ++e){
    const float hn = hg[8+e];
    const float sp = (hn > 20.f) ? hn : log1pf(expf(hn));
    h[e] = hg[e] + noise[(size_t)t*NEXP + e] + sp;
  }

  int kk = *kp; kk = kk<1?1:(kk>NEXP?NEXP:kk);
  bool used[NEXP];
  #pragma unroll
  for (int e=0;e<NEXP;e++) used[e]=false;
  float kth = 0.f;
  for (int i=0;i<kk;i++){
    int bi=0; float bv=-3.4e38f;
    #pragma unroll
    for (int e=0;e<NEXP;e++) if (!used[e] && h[e]>bv){bv=h[e]; bi=e;}
    used[bi]=true; kth=bv;
  }
  float m=-3.4e38f;
  #pragma unroll
  for (int e=0;e<NEXP;e++) if (h[e]>=kth && h[e]>m) m=h[e];
  float p[NEXP], s=0.f;
  #pragma unroll
  for (int e=0;e<NEXP;e++){ p[e]=(h[e]>=kth)?expf(h[e]-m):0.f; s+=p[e]; }
  const float inv = 1.f/s;
  float g[NEXP];
  int lslot[NEXP];
  #pragma unroll
  for (int e=0;e<NEXP;e++){
    g[e] = p[e]*inv;
    gates[(size_t)t*NEXP + e] = g[e];
    if (g[e] > 0.f) lslot[e] = atomicAdd(&lcnt[e], 1);
  }
  __syncthreads();
  if (tid < NEXP) lbase[tid] = atomicAdd(&counts[tid], lcnt[tid]);
  __syncthreads();
  int idx = 0;
  #pragma unroll
  for (int e=0;e<NEXP;e++){
    if (g[e] > 0.f){
      const int slot = lbase[e] + lslot[e];
      lists[e*BTOK + slot] = t;
      tokmap[t*NEXP + idx] = (e << 13) | (slot & 8191);
      idx++;
    }
  }
  ncnt[t] = idx;
}

// ---------------- transpose+cast W1,W2 -> bf16 WT[e][n][k] ----------------
__global__ __launch_bounds__(256) void trans_kernel(
    const float* __restrict__ W1, const float* __restrict__ W2,
    u16* __restrict__ W1T, u16* __restrict__ W2T)
{
  __shared__ float tile[64][65];
  const int mz = blockIdx.z;
  const float* src = (mz < NEXP) ? (W1  + (size_t)mz*DDIM*DDIM) : (W2  + (size_t)(mz-NEXP)*DDIM*DDIM);
  u16*       dst = (mz < NEXP) ? (W1T + (size_t)mz*DDIM*DDIM) : (W2T + (size_t)(mz-NEXP)*DDIM*DDIM);
  const int r0 = blockIdx.x*64, c0 = blockIdx.y*64;
  const int tx = threadIdx.x & 63, ty = threadIdx.x >> 6;
  #pragma unroll
  for (int i=ty;i<64;i+=4)
    tile[i][tx] = src[(size_t)(r0+i)*DDIM + c0+tx];
  __syncthreads();
  #pragma unroll
  for (int i=ty;i<64;i+=4)
    dst[(size_t)(c0+i)*DDIM + r0+tx] = f2bf(tile[tx][i]);
}

// ---- expert FFN GEMM: 256x256xBK32, 8 waves, single-barrier 2-phase, expert->XCD ----
template<int LAYER>
__device__ __forceinline__ void ffn_body(
    const u16* __restrict__ Asrc, const u16* __restrict__ WT,
    const float* __restrict__ bias,
    const int* __restrict__ counts, const int* __restrict__ lists,
    u16* __restrict__ dst)
{
  // 1D grid, expert = wgid & 7 so each expert's blocks land on one XCD (L2 locality)
  const int lin = blockIdx.x;
  const int e   = lin & 7;
  const int idx = lin >> 3;                 // 0..47
  const int m0  = (idx >> 2) * BM;          // 12 m-blocks
  const int n0  = (idx & 3)  * BN;          // 4 n-blocks
  int cnt = counts[e]; if (cnt > SLOTCAP) cnt = SLOTCAP;
  if (m0 >= cnt) return;                    // uniform early-exit (before any barrier)

  __shared__ __align__(16) u16 ldsA[2][BM*BK];   // 2 x 16 KB
  __shared__ __align__(16) u16 ldsB[2][BN*BK];   // 2 x 16 KB

  const int tid = threadIdx.x;
  const int wave = tid>>6, lane = tid&63;
  const int wm = wave>>2, wn = wave&3;           // 2M x 4N waves

  // staging: per wave 2 chunks/matrix; chunk = 16 rows; lane covers row (lane>>2),
  // physical 16B slot (lane&3). Source pre-swizzled: logical slot = phys ^ (row&3).
  const u16* aSrc[2]; const u16* bSrc[2];
  {
    const int lr = lane>>2, sp = lane&3;
    #pragma unroll
    for (int i=0;i<2;i++){
      const int row = wave*32 + i*16 + lr;       // 0..255
      const int ku  = sp ^ (row&3);
      size_t abase;
      if constexpr (LAYER==1){
        int gr = m0 + row; if (gr >= cnt) gr = cnt-1;   // clamp: dup rows
        abase = (size_t)lists[e*BTOK + gr] * DDIM;
      } else {
        abase = ((size_t)e*SLOTCAP + m0 + row) * DDIM;
      }
      aSrc[i] = Asrc + abase + ku*8;
      bSrc[i] = WT + ((size_t)e*DDIM + n0 + row)*DDIM + ku*8;
    }
  }

  const int q = lane>>4, l16 = lane&15;
  // swizzled ds_read offsets (u16 units): row r, slot q -> r*32 + ((q ^ (r&3))*8)
  int aoff[8], boff[4];
  #pragma unroll
  for (int f=0;f<8;f++){
    const int ra = wm*128 + f*16 + l16;
    aoff[f] = ra*BK + ((q ^ (ra&3))*8);
  }
  #pragma unroll
  for (int f=0;f<4;f++){
    const int rb = wn*64 + f*16 + l16;
    boff[f] = rb*BK + ((q ^ (rb&3))*8);
  }

  f32x4 acc[8][4];
  #pragma unroll
  for (int i=0;i<8;i++)
    #pragma unroll
    for (int j=0;j<4;j++)
      acc[i][j] = (f32x4){0.f,0.f,0.f,0.f};

  #define STAGE(T, c)                                               \
    _Pragma("unroll")                                               \
    for (int i=0;i<2;i++){                                          \
      gll16(aSrc[i] + (size_t)(T)*BK, &ldsA[c][(wave*32+i*16)*BK]); \
      gll16(bSrc[i] + (size_t)(T)*BK, &ldsB[c][(wave*32+i*16)*BK]); \
    }
  #define COMPUTE(c)                                                           \
    {                                                                          \
      short8 bfr[4], afr[8];                                                   \
      _Pragma("unroll")                                                        \
      for (int f=0;f<4;f++) bfr[f] = *reinterpret_cast<const short8*>(&ldsB[c][boff[f]]); \
      _Pragma("unroll")                                                        \
      for (int f=0;f<8;f++) afr[f] = *reinterpret_cast<const short8*>(&ldsA[c][aoff[f]]); \
      _Pragma("unroll")                                                        \
      for (int fm=0;fm<8;fm++)                                                 \
        _Pragma("unroll")                                                      \
        for (int fn=0;fn<4;fn++)                                               \
          acc[fm][fn] = __builtin_amdgcn_mfma_f32_16x16x32_bf16(afr[fm], bfr[fn], acc[fm][fn], 0, 0, 0); \
    }

  STAGE(0, 0)
  __syncthreads();
  int cur = 0;
  for (int kt = 0; kt < NT-1; ++kt){
    STAGE(kt+1, cur^1)       // issue next-tile loads first (full compute phase to land)
    COMPUTE(cur)
    __syncthreads();         // vmcnt(0)+lgkmcnt(0)+barrier: next buf ready, reads done
    cur ^= 1;
  }
  COMPUTE(cur)
  #undef STAGE
  #undef COMPUTE

  // epilogue: C/D layout col=lane&15, row=(lane>>4)*4+reg
  #pragma unroll
  for (int fm=0;fm<8;fm++){
    #pragma unroll
    for (int r=0;r<4;r++){
      const int row = wm*128 + fm*16 + q*4 + r;
      const int gr  = m0 + row;                 // < SLOTCAP by grid
      #pragma unroll
      for (int fn=0;fn<4;fn++){
        const int col = n0 + wn*64 + fn*16 + l16;
        float v = acc[fm][fn][r] + bias[e*DDIM + col];
        if constexpr (LAYER==1) v = v > 0.f ? v : 0.f;
        dst[((size_t)e*SLOTCAP + gr)*DDIM + col] = f2bf(v);
      }
    }
  }
}

__global__ __launch_bounds__(512, 4) void ffn1_kernel(
    const u16* __restrict__ A, const u16* __restrict__ WT, const float* __restrict__ b,
    const int* __restrict__ counts, const int* __restrict__ lists, u16* __restrict__ dst)
{ ffn_body<1>(A, WT, b, counts, lists, dst); }

__global__ __launch_bounds__(512, 4) void ffn2_kernel(
    const u16* __restrict__ A, const u16* __restrict__ WT, const float* __restrict__ b,
    const int* __restrict__ counts, const int* __restrict__ lists, u16* __restrict__ dst)
{ ffn_body<2>(A, WT, b, counts, lists, dst); }

// ---------------- combine ----------------
__global__ __launch_bounds__(256) void combine_kernel(
    const u16* __restrict__ partial, const int* __restrict__ tokmap,
    const int* __restrict__ ncnt, const float* __restrict__ gates,
    float* __restrict__ out)
{
  const int t = blockIdx.x, c = threadIdx.x;
  const int n = ncnt[t];
  float4 acc = {0.f, 0.f, 0.f, 0.f};
  for (int j = 0; j < n; ++j){
    const int ent  = tokmap[t*NEXP + j];
    const int e    = ent >> 13, slot = ent & 8191;
    if (slot >= SLOTCAP) continue;
    const float g = gates[(size_t)t*NEXP + e];
    const ushort4 pv = reinterpret_cast<const ushort4*>(
        partial + ((size_t)e*SLOTCAP + slot)*DDIM)[c];
    acc.x = fmaf(g, bf2f(pv.x), acc.x);
    acc.y = fmaf(g, bf2f(pv.y), acc.y);
    acc.z = fmaf(g, bf2f(pv.z), acc.z);
    acc.w = fmaf(g, bf2f(pv.w), acc.w);
  }
  reinterpret_cast<float4*>(out + (size_t)t*DDIM)[c] = acc;
}

// ---------------- host launch ----------------
extern "C" void kernel_launch(void* const* d_in, const int* in_sizes, int n_in,
                              void* d_out, int out_size, void* d_ws, size_t ws_size,
                              hipStream_t stream)
{
  const float* x     = (const float*)d_in[0];
  const float* noise = (const float*)d_in[1];
  const float* Wg    = (const float*)d_in[2];
  const float* Wn    = (const float*)d_in[3];
  const float* W1    = (const float*)d_in[4];
  const float* b1    = (const float*)d_in[5];
  const float* W2    = (const float*)d_in[6];
  const float* b2    = (const float*)d_in[7];
  const int*   kp    = (const int*)d_in[8];
  float* out = (float*)d_out;

  char* ws = (char*)d_ws;
  int*   counts = (int*)ws;                      // 4K
  int*   lists  = (int*)(ws + 4096);             // 256K
  float* gates  = (float*)(ws + 266240);         // 256K
  int*   tokmap = (int*)(ws + 528384);           // 256K
  int*   ncnt   = (int*)(ws + 790528);           // 32K
  u16*   xb     = (u16*)(ws + 823296);           // 16.78M
  u16*   W1T    = (u16*)(ws + 17600512);         // 16.78M
  u16*   W2T    = (u16*)(ws + 34377728);         // 16.78M
  u16*   hidden = (u16*)(ws + 51154944);         // 50.33M
  u16*   partial= (u16*)(ws + 101486592);        // 50.33M
  // transient aliases inside `partial` (dead before ffn2 writes it):
  float* hp     = (float*)(ws + 101486592);      // 512K  h'[8192][16]
  u16*   wpt    = (u16*)(ws + 102010880);        // 64K   W'T hi/lo
  const size_t NEED = 151818240ull;

  hipMemsetAsync(counts, 0, 64, stream);
  if (ws_size < NEED){
    hipMemsetAsync(d_out, 0, (size_t)out_size*sizeof(float), stream);
    return;
  }

  cast_x_kernel<<<BTOK*DDIM/4/256, 256, 0, stream>>>((const float4*)x, (ushort4*)xb);
  wprep_kernel<<<64, 256, 0, stream>>>(Wg, Wn, wpt);
  trans_kernel<<<dim3(16,16,16), 256, 0, stream>>>(W1, W2, W1T, W2T);
  score_kernel<<<BTOK/32, 128, 0, stream>>>(x, xb, wpt, hp);
  gating_select_kernel<<<BTOK/256, 256, 0, stream>>>(hp, noise, kp, gates, counts, lists,
                                                     tokmap, ncnt);
  ffn1_kernel<<<(SLOTCAP/BM)*4*NEXP, 512, 0, stream>>>(
      xb, W1T, b1, counts, lists, hidden);
  ffn2_kernel<<<(SLOTCAP/BM)*4*NEXP, 512, 0, stream>>>(
      hidden, W2T, b2, counts, lists, partial);
  combine_kernel<<<BTOK, 256, 0, stream>>>(partial, tokmap, ncnt, gates, out);
}

// Round 8
// 328.208 us; speedup vs baseline: 2.2686x; 2.2686x over previous
//
#include <hip/hip_runtime.h>
#include <hip/hip_bf16.h>

#define BTOK 8192
#define DDIM 1024
#define NEXP 8

typedef unsigned short u16;
typedef unsigned int u32;
typedef __attribute__((ext_vector_type(8))) short short8;
typedef __attribute__((ext_vector_type(4))) float f32x4;

constexpr int BM = 256, BN = 256, BK = 64;
constexpr int SLOTCAP = 3072;
constexpr int NT = DDIM / BK;          // 16 K-tiles

__device__ __forceinline__ u16 f2bf(float f){
  __hip_bfloat16 h = __float2bfloat16(f);
  return *reinterpret_cast<u16*>(&h);
}
__device__ __forceinline__ float bf2f(u16 v){
  return __uint_as_float(((u32)v) << 16);
}
__device__ __forceinline__ void gll16(const u16* gsrc, u16* ldst){
  __builtin_amdgcn_global_load_lds((const __attribute__((address_space(1))) void*)gsrc,
                                   (__attribute__((address_space(3))) void*)ldst,
                                   16, 0, 0);
}

// ---------------- cast x -> bf16 ----------------
__global__ __launch_bounds__(256) void cast_x_kernel(const float4* __restrict__ x4,
                                                     ushort4* __restrict__ xb4)
{
  const int i = blockIdx.x*256 + threadIdx.x;
  const float4 v = x4[i];
  xb4[i] = make_ushort4(f2bf(v.x), f2bf(v.y), f2bf(v.z), f2bf(v.w));
}

// ---------------- W' prep: W'T[n][d] hi/lo bf16, n<8 = Wg col, n>=8 = Wn col ----------------
__global__ __launch_bounds__(256) void wprep_kernel(
    const float* __restrict__ Wg, const float* __restrict__ Wn,
    u16* __restrict__ wpt)
{
  const int idx = blockIdx.x*256 + threadIdx.x;     // 16384 = 16 n x 1024 d
  const int n = idx >> 10, d = idx & 1023;
  const float v = (n < 8) ? Wg[d*8 + n] : Wn[d*8 + (n-8)];
  const u16 hi = f2bf(v);
  const u16 lo = f2bf(v - bf2f(hi));
  wpt[n*1024 + d]          = hi;
  wpt[16384 + n*1024 + d]  = lo;
}

// ---------------- gating score: h' = x @ W' via split-bf16 MFMA ----------------
__global__ __launch_bounds__(128) void score_kernel(
    const float* __restrict__ x, const u16* __restrict__ xb,
    const u16* __restrict__ wpt, float* __restrict__ hp)
{
  __shared__ __align__(16) u16 lw[2][16][1024];   // 64 KB
  const int tid = threadIdx.x;
  const int wave = tid >> 6, lane = tid & 63;

  for (int it = 0; it < 32; ++it){
    const int cid = it*128 + tid;                 // 0..4095 (16B chunks)
    const int v = cid >> 11, rem = cid & 2047;
    const int n = rem >> 7, c = rem & 127;
    const short8 val = *reinterpret_cast<const short8*>(wpt + v*16384 + n*1024 + c*8);
    *reinterpret_cast<short8*>(&lw[v][n][(c ^ (n&7))*8]) = val;
  }
  __syncthreads();

  const int q = lane >> 4, l16 = lane & 15;
  const int t0 = blockIdx.x*32 + wave*16;
  const int rowA = t0 + l16;
  const u16*   xbp = xb + (size_t)rowA*DDIM + q*8;
  const float* xp  = x  + (size_t)rowA*DDIM + q*8;

  f32x4 acc0 = {0.f,0.f,0.f,0.f}, acc1 = acc0, acc2 = acc0;
  for (int kt = 0; kt < 32; ++kt){
    const short8 ah = *reinterpret_cast<const short8*>(xbp + kt*32);
    const float4 x0 = *reinterpret_cast<const float4*>(xp + kt*32);
    const float4 x1 = *reinterpret_cast<const float4*>(xp + kt*32 + 4);
    short8 al;
    al[0]=(short)f2bf(x0.x - bf2f((u16)ah[0])); al[1]=(short)f2bf(x0.y - bf2f((u16)ah[1]));
    al[2]=(short)f2bf(x0.z - bf2f((u16)ah[2])); al[3]=(short)f2bf(x0.w - bf2f((u16)ah[3]));
    al[4]=(short)f2bf(x1.x - bf2f((u16)ah[4])); al[5]=(short)f2bf(x1.y - bf2f((u16)ah[5]));
    al[6]=(short)f2bf(x1.z - bf2f((u16)ah[6])); al[7]=(short)f2bf(x1.w - bf2f((u16)ah[7]));
    const int bs = ((kt*4 + q) ^ (l16 & 7)) * 8;
    const short8 bh = *reinterpret_cast<const short8*>(&lw[0][l16][bs]);
    const short8 bl = *reinterpret_cast<const short8*>(&lw[1][l16][bs]);
    acc0 = __builtin_amdgcn_mfma_f32_16x16x32_bf16(ah, bh, acc0, 0, 0, 0);
    acc1 = __builtin_amdgcn_mfma_f32_16x16x32_bf16(al, bh, acc1, 0, 0, 0);
    acc2 = __builtin_amdgcn_mfma_f32_16x16x32_bf16(ah, bl, acc2, 0, 0, 0);
  }
  #pragma unroll
  for (int r = 0; r < 4; ++r)
    hp[(size_t)(t0 + q*4 + r)*16 + l16] = acc0[r] + acc1[r] + acc2[r];
}

// ---------------- gating select ----------------
__global__ __launch_bounds__(256) void gating_select_kernel(
    const float* __restrict__ hp, const float* __restrict__ noise,
    const int* __restrict__ kp,
    float* __restrict__ gates, int* __restrict__ counts, int* __restrict__ lists,
    int* __restrict__ tokmap, int* __restrict__ ncnt)
{
  __shared__ int lcnt[NEXP];
  __shared__ int lbase[NEXP];
  const int tid = threadIdx.x;
  const int t   = blockIdx.x*256 + tid;
  if (tid < NEXP) lcnt[tid] = 0;
  __syncthreads();

  float hg[16];
  #pragma unroll
  for (int i = 0; i < 4; ++i){
    const float4 v = reinterpret_cast<const float4*>(hp + (size_t)t*16)[i];
    hg[i*4+0]=v.x; hg[i*4+1]=v.y; hg[i*4+2]=v.z; hg[i*4+3]=v.w;
  }
  float h[NEXP];
  #pragma unroll
  for (int e = 0; e < NEXP; ++e){
    const float hn = hg[8+e];
    const float sp = (hn > 20.f) ? hn : log1pf(expf(hn));
    h[e] = hg[e] + noise[(size_t)t*NEXP + e] + sp;
  }

  int kk = *kp; kk = kk<1?1:(kk>NEXP?NEXP:kk);
  bool used[NEXP];
  #pragma unroll
  for (int e=0;e<NEXP;e++) used[e]=false;
  float kth = 0.f;
  for (int i=0;i<kk;i++){
    int bi=0; float bv=-3.4e38f;
    #pragma unroll
    for (int e=0;e<NEXP;e++) if (!used[e] && h[e]>bv){bv=h[e]; bi=e;}
    used[bi]=true; kth=bv;
  }
  float m=-3.4e38f;
  #pragma unroll
  for (int e=0;e<NEXP;e++) if (h[e]>=kth && h[e]>m) m=h[e];
  float p[NEXP], s=0.f;
  #pragma unroll
  for (int e=0;e<NEXP;e++){ p[e]=(h[e]>=kth)?expf(h[e]-m):0.f; s+=p[e]; }
  const float inv = 1.f/s;
  float g[NEXP];
  int lslot[NEXP];
  #pragma unroll
  for (int e=0;e<NEXP;e++){
    g[e] = p[e]*inv;
    gates[(size_t)t*NEXP + e] = g[e];
    if (g[e] > 0.f) lslot[e] = atomicAdd(&lcnt[e], 1);
  }
  __syncthreads();
  if (tid < NEXP) lbase[tid] = atomicAdd(&counts[tid], lcnt[tid]);
  __syncthreads();
  int idx = 0;
  #pragma unroll
  for (int e=0;e<NEXP;e++){
    if (g[e] > 0.f){
      const int slot = lbase[e] + lslot[e];
      lists[e*BTOK + slot] = t;
      tokmap[t*NEXP + idx] = (e << 13) | (slot & 8191);
      idx++;
    }
  }
  ncnt[t] = idx;
}

// ---------------- transpose+cast W1,W2 -> bf16 WT[e][n][k] ----------------
__global__ __launch_bounds__(256) void trans_kernel(
    const float* __restrict__ W1, const float* __restrict__ W2,
    u16* __restrict__ W1T, u16* __restrict__ W2T)
{
  __shared__ float tile[64][65];
  const int mz = blockIdx.z;
  const float* src = (mz < NEXP) ? (W1  + (size_t)mz*DDIM*DDIM) : (W2  + (size_t)(mz-NEXP)*DDIM*DDIM);
  u16*       dst = (mz < NEXP) ? (W1T + (size_t)mz*DDIM*DDIM) : (W2T + (size_t)(mz-NEXP)*DDIM*DDIM);
  const int r0 = blockIdx.x*64, c0 = blockIdx.y*64;
  const int tx = threadIdx.x & 63, ty = threadIdx.x >> 6;
  #pragma unroll
  for (int i=ty;i<64;i+=4)
    tile[i][tx] = src[(size_t)(r0+i)*DDIM + c0+tx];
  __syncthreads();
  #pragma unroll
  for (int i=ty;i<64;i+=4)
    dst[(size_t)(c0+i)*DDIM + r0+tx] = f2bf(tile[tx][i]);
}

// ---- expert FFN GEMM: 256x256xBK64, 8 waves, counted-vmcnt pipeline (T3+T4+T5) ----
// Ledger: prologue stages t0,t1 (16 loads in flight), vmcnt(8) -> t0 ready.
// Per iter: compute buf c | barrier A | STAGE(kt+2 -> buf c) ; vmcnt(8)
// (drains only tile kt+1's 8 loads, keeps kt+2's 8 in flight) | barrier B.
// Tail: no stage -> vmcnt(0). 1 block/CU (128 KB LDS), VGPR budget 256.
template<int LAYER>
__device__ __forceinline__ void ffn_body(
    const u16* __restrict__ Asrc, const u16* __restrict__ WT,
    const float* __restrict__ bias,
    const int* __restrict__ counts, const int* __restrict__ lists,
    u16* __restrict__ dst)
{
  // 1D grid: expert = wgid & 7 -> all of an expert's blocks on one XCD (L2 reuse)
  const int lin = blockIdx.x;
  const int e   = lin & 7;
  const int idx = lin >> 3;                 // 0..47
  const int m0  = (idx >> 2) * BM;          // 12 m-blocks
  const int n0  = (idx & 3)  * BN;          // 4 n-blocks
  int cnt = counts[e]; if (cnt > SLOTCAP) cnt = SLOTCAP;
  if (m0 >= cnt) return;                    // uniform early-exit (before any barrier)

  __shared__ __align__(16) u16 ldsA[2][BM*BK];   // 64 KB
  __shared__ __align__(16) u16 ldsB[2][BN*BK];   // 64 KB

  const int tid = threadIdx.x;
  const int wave = tid>>6, lane = tid&63;
  const int wm = wave>>2, wn = wave&3;           // 2M x 4N waves

  // staging sources (T2 both-sides rule: linear LDS dest, pre-swizzled global src)
  const u16* aSrc[4]; const u16* bSrc[4];
  {
    const int lr = lane>>3, sp = lane&7;
    #pragma unroll
    for (int i=0;i<4;i++){
      const int row = wave*32 + i*8 + lr;        // 0..255
      const int ku  = sp ^ (row&7);
      size_t abase;
      if constexpr (LAYER==1){
        int gr = m0 + row; if (gr >= cnt) gr = cnt-1;   // clamp: dup rows
        abase = (size_t)lists[e*BTOK + gr] * DDIM;
      } else {
        abase = ((size_t)e*SLOTCAP + m0 + row) * DDIM;
      }
      aSrc[i] = Asrc + abase + ku*8;
      bSrc[i] = WT + ((size_t)e*DDIM + n0 + row)*DDIM + ku*8;
    }
  }

  const int q = lane>>4, l16 = lane&15;
  // swizzled ds_read offsets (u16 units) for kk=0; kk=1 is ^32 (slot bit2 flip)
  int aoff[8], boff[4];
  #pragma unroll
  for (int f=0;f<8;f++){
    const int ra = wm*128 + f*16 + l16;
    aoff[f] = ra*BK + ((q ^ (ra&7))*8);
  }
  #pragma unroll
  for (int f=0;f<4;f++){
    const int rb = wn*64 + f*16 + l16;
    boff[f] = rb*BK + ((q ^ (rb&7))*8);
  }

  f32x4 acc[8][4];
  #pragma unroll
  for (int i=0;i<8;i++)
    #pragma unroll
    for (int j=0;j<4;j++)
      acc[i][j] = (f32x4){0.f,0.f,0.f,0.f};

  #define STAGE(T, c)                                            \
    _Pragma("unroll")                                            \
    for (int i=0;i<4;i++){                                       \
      gll16(aSrc[i] + (size_t)(T)*BK, &ldsA[c][(wave*32+i*8)*BK]); \
      gll16(bSrc[i] + (size_t)(T)*BK, &ldsB[c][(wave*32+i*8)*BK]); \
    }

  // prologue: stage tiles 0 and 1 (16 loads in flight), wait for tile 0 only
  STAGE(0, 0)
  STAGE(1, 1)
  asm volatile("s_waitcnt vmcnt(8)" ::: "memory");
  __builtin_amdgcn_sched_barrier(0);
  __builtin_amdgcn_s_barrier();
  __builtin_amdgcn_sched_barrier(0);

  for (int kt = 0; kt < NT; ++kt){
    const int c = kt & 1;
    // ---- compute tile kt from buf c ----
    #pragma unroll
    for (int kk=0; kk<2; kk++){
      const int kx = kk ? 32 : 0;
      short8 bfr[4], afr[8];
      #pragma unroll
      for (int f=0;f<4;f++) bfr[f] = *reinterpret_cast<const short8*>(&ldsB[c][boff[f] ^ kx]);
      #pragma unroll
      for (int f=0;f<8;f++) afr[f] = *reinterpret_cast<const short8*>(&ldsA[c][aoff[f] ^ kx]);
      __builtin_amdgcn_s_setprio(1);
      #pragma unroll
      for (int fm=0;fm<8;fm++)
        #pragma unroll
        for (int fn=0;fn<4;fn++)
          acc[fm][fn] = __builtin_amdgcn_mfma_f32_16x16x32_bf16(afr[fm], bfr[fn], acc[fm][fn], 0, 0, 0);
      __builtin_amdgcn_s_setprio(0);
    }
    // ---- barrier (A): all waves done reading buf c ----
    __builtin_amdgcn_sched_barrier(0);
    __builtin_amdgcn_s_barrier();
    __builtin_amdgcn_sched_barrier(0);
    // ---- stage tile kt+2 into buf c; wait only for tile kt+1's loads ----
    if (kt + 2 < NT){
      STAGE(kt+2, c)
      asm volatile("s_waitcnt vmcnt(8)" ::: "memory");
    } else {
      asm volatile("s_waitcnt vmcnt(0)" ::: "memory");
    }
    __builtin_amdgcn_sched_barrier(0);
    __builtin_amdgcn_s_barrier();          // (B): buf c^1 (tile kt+1) ready
    __builtin_amdgcn_sched_barrier(0);
  }
  #undef STAGE

  // epilogue: C/D layout col=lane&15, row=(lane>>4)*4+reg
  #pragma unroll
  for (int fm=0;fm<8;fm++){
    #pragma unroll
    for (int r=0;r<4;r++){
      const int row = wm*128 + fm*16 + q*4 + r;
      const int gr  = m0 + row;                 // < SLOTCAP by grid
      #pragma unroll
      for (int fn=0;fn<4;fn++){
        const int col = n0 + wn*64 + fn*16 + l16;
        float v = acc[fm][fn][r] + bias[e*DDIM + col];
        if constexpr (LAYER==1) v = v > 0.f ? v : 0.f;
        dst[((size_t)e*SLOTCAP + gr)*DDIM + col] = f2bf(v);
      }
    }
  }
}

__global__ __launch_bounds__(512, 1) void ffn1_kernel(
    const u16* __restrict__ A, const u16* __restrict__ WT, const float* __restrict__ b,
    const int* __restrict__ counts, const int* __restrict__ lists, u16* __restrict__ dst)
{ ffn_body<1>(A, WT, b, counts, lists, dst); }

__global__ __launch_bounds__(512, 1) void ffn2_kernel(
    const u16* __restrict__ A, const u16* __restrict__ WT, const float* __restrict__ b,
    const int* __restrict__ counts, const int* __restrict__ lists, u16* __restrict__ dst)
{ ffn_body<2>(A, WT, b, counts, lists, dst); }

// ---------------- combine ----------------
__global__ __launch_bounds__(256) void combine_kernel(
    const u16* __restrict__ partial, const int* __restrict__ tokmap,
    const int* __restrict__ ncnt, const float* __restrict__ gates,
    float* __restrict__ out)
{
  const int t = blockIdx.x, c = threadIdx.x;
  const int n = ncnt[t];
  float4 acc = {0.f, 0.f, 0.f, 0.f};
  for (int j = 0; j < n; ++j){
    const int ent  = tokmap[t*NEXP + j];
    const int e    = ent >> 13, slot = ent & 8191;
    if (slot >= SLOTCAP) continue;
    const float g = gates[(size_t)t*NEXP + e];
    const ushort4 pv = reinterpret_cast<const ushort4*>(
        partial + ((size_t)e*SLOTCAP + slot)*DDIM)[c];
    acc.x = fmaf(g, bf2f(pv.x), acc.x);
    acc.y = fmaf(g, bf2f(pv.y), acc.y);
    acc.z = fmaf(g, bf2f(pv.z), acc.z);
    acc.w = fmaf(g, bf2f(pv.w), acc.w);
  }
  reinterpret_cast<float4*>(out + (size_t)t*DDIM)[c] = acc;
}

// ---------------- host launch ----------------
extern "C" void kernel_launch(void* const* d_in, const int* in_sizes, int n_in,
                              void* d_out, int out_size, void* d_ws, size_t ws_size,
                              hipStream_t stream)
{
  const float* x     = (const float*)d_in[0];
  const float* noise = (const float*)d_in[1];
  const float* Wg    = (const float*)d_in[2];
  const float* Wn    = (const float*)d_in[3];
  const float* W1    = (const float*)d_in[4];
  const float* b1    = (const float*)d_in[5];
  const float* W2    = (const float*)d_in[6];
  const float* b2    = (const float*)d_in[7];
  const int*   kp    = (const int*)d_in[8];
  float* out = (float*)d_out;

  char* ws = (char*)d_ws;
  int*   counts = (int*)ws;                      // 4K
  int*   lists  = (int*)(ws + 4096);             // 256K
  float* gates  = (float*)(ws + 266240);         // 256K
  int*   tokmap = (int*)(ws + 528384);           // 256K
  int*   ncnt   = (int*)(ws + 790528);           // 32K
  u16*   xb     = (u16*)(ws + 823296);           // 16.78M
  u16*   W1T    = (u16*)(ws + 17600512);         // 16.78M
  u16*   W2T    = (u16*)(ws + 34377728);         // 16.78M
  u16*   hidden = (u16*)(ws + 51154944);         // 50.33M
  u16*   partial= (u16*)(ws + 101486592);        // 50.33M
  // transient aliases inside `partial` (dead before ffn2 writes it):
  float* hp     = (float*)(ws + 101486592);      // 512K  h'[8192][16]
  u16*   wpt    = (u16*)(ws + 102010880);        // 64K   W'T hi/lo
  const size_t NEED = 151818240ull;

  hipMemsetAsync(counts, 0, 64, stream);
  if (ws_size < NEED){
    hipMemsetAsync(d_out, 0, (size_t)out_size*sizeof(float), stream);
    return;
  }

  cast_x_kernel<<<BTOK*DDIM/4/256, 256, 0, stream>>>((const float4*)x, (ushort4*)xb);
  wprep_kernel<<<64, 256, 0, stream>>>(Wg, Wn, wpt);
  trans_kernel<<<dim3(16,16,16), 256, 0, stream>>>(W1, W2, W1T, W2T);
  score_kernel<<<BTOK/32, 128, 0, stream>>>(x, xb, wpt, hp);
  gating_select_kernel<<<BTOK/256, 256, 0, stream>>>(hp, noise, kp, gates, counts, lists,
                                                     tokmap, ncnt);
  ffn1_kernel<<<(SLOTCAP/BM)*4*NEXP, 512, 0, stream>>>(
      xb, W1T, b1, counts, lists, hidden);
  ffn2_kernel<<<(SLOTCAP/BM)*4*NEXP, 512, 0, stream>>>(
      hidden, W2T, b2, counts, lists, partial);
  combine_kernel<<<BTOK, 256, 0, stream>>>(partial, tokmap, ncnt, gates, out);
}

// Round 9
// 324.005 us; speedup vs baseline: 2.2980x; 1.0130x over previous
//
#include <hip/hip_runtime.h>
#include <hip/hip_bf16.h>

#define BTOK 8192
#define DDIM 1024
#define NEXP 8

typedef unsigned short u16;
typedef unsigned int u32;
typedef __attribute__((ext_vector_type(8))) short short8;
typedef __attribute__((ext_vector_type(4))) float f32x4;

constexpr int BM = 256, BN = 256, BK = 64;
constexpr int SLOTCAP = 3072;
constexpr int NT = DDIM / BK;          // 16 K-tiles

__device__ __forceinline__ u16 f2bf(float f){
  __hip_bfloat16 h = __float2bfloat16(f);
  return *reinterpret_cast<u16*>(&h);
}
__device__ __forceinline__ float bf2f(u16 v){
  return __uint_as_float(((u32)v) << 16);
}
__device__ __forceinline__ void gll16(const u16* gsrc, u16* ldst){
  __builtin_amdgcn_global_load_lds((const __attribute__((address_space(1))) void*)gsrc,
                                   (__attribute__((address_space(3))) void*)ldst,
                                   16, 0, 0);
}

// ---------------- W' prep: W'T[n][d] hi/lo bf16, n<8 = Wg col, n>=8 = Wn col ----------------
__global__ __launch_bounds__(256) void wprep_kernel(
    const float* __restrict__ Wg, const float* __restrict__ Wn,
    u16* __restrict__ wpt)
{
  const int idx = blockIdx.x*256 + threadIdx.x;     // 16384 = 16 n x 1024 d
  const int n = idx >> 10, d = idx & 1023;
  const float v = (n < 8) ? Wg[d*8 + n] : Wn[d*8 + (n-8)];
  const u16 hi = f2bf(v);
  const u16 lo = f2bf(v - bf2f(hi));
  wpt[n*1024 + d]          = hi;
  wpt[16384 + n*1024 + d]  = lo;
}

// ------- gating score: h' = x @ W' via split-bf16 MFMA; also emits xb (x as bf16) -------
__global__ __launch_bounds__(128) void score_kernel(
    const float* __restrict__ x, const u16* __restrict__ wpt,
    float* __restrict__ hp, u16* __restrict__ xb)
{
  __shared__ __align__(16) u16 lw[2][16][1024];   // 64 KB
  const int tid = threadIdx.x;
  const int wave = tid >> 6, lane = tid & 63;

  for (int it = 0; it < 32; ++it){
    const int cid = it*128 + tid;                 // 0..4095 (16B chunks)
    const int v = cid >> 11, rem = cid & 2047;
    const int n = rem >> 7, c = rem & 127;
    const short8 val = *reinterpret_cast<const short8*>(wpt + v*16384 + n*1024 + c*8);
    *reinterpret_cast<short8*>(&lw[v][n][(c ^ (n&7))*8]) = val;
  }
  __syncthreads();

  const int q = lane >> 4, l16 = lane & 15;
  const int t0 = blockIdx.x*32 + wave*16;
  const int rowA = t0 + l16;
  const float* xp  = x  + (size_t)rowA*DDIM + q*8;
  u16*         xbo = xb + (size_t)rowA*DDIM + q*8;

  f32x4 acc0 = {0.f,0.f,0.f,0.f}, acc1 = acc0, acc2 = acc0;
  for (int kt = 0; kt < 32; ++kt){
    const float4 x0 = *reinterpret_cast<const float4*>(xp + kt*32);
    const float4 x1 = *reinterpret_cast<const float4*>(xp + kt*32 + 4);
    short8 ah;
    ah[0]=(short)f2bf(x0.x); ah[1]=(short)f2bf(x0.y);
    ah[2]=(short)f2bf(x0.z); ah[3]=(short)f2bf(x0.w);
    ah[4]=(short)f2bf(x1.x); ah[5]=(short)f2bf(x1.y);
    ah[6]=(short)f2bf(x1.z); ah[7]=(short)f2bf(x1.w);
    *reinterpret_cast<short8*>(xbo + kt*32) = ah;   // fused x->bf16 cast
    short8 al;
    al[0]=(short)f2bf(x0.x - bf2f((u16)ah[0])); al[1]=(short)f2bf(x0.y - bf2f((u16)ah[1]));
    al[2]=(short)f2bf(x0.z - bf2f((u16)ah[2])); al[3]=(short)f2bf(x0.w - bf2f((u16)ah[3]));
    al[4]=(short)f2bf(x1.x - bf2f((u16)ah[4])); al[5]=(short)f2bf(x1.y - bf2f((u16)ah[5]));
    al[6]=(short)f2bf(x1.z - bf2f((u16)ah[6])); al[7]=(short)f2bf(x1.w - bf2f((u16)ah[7]));
    const int bs = ((kt*4 + q) ^ (l16 & 7)) * 8;
    const short8 bh = *reinterpret_cast<const short8*>(&lw[0][l16][bs]);
    const short8 bl = *reinterpret_cast<const short8*>(&lw[1][l16][bs]);
    acc0 = __builtin_amdgcn_mfma_f32_16x16x32_bf16(ah, bh, acc0, 0, 0, 0);
    acc1 = __builtin_amdgcn_mfma_f32_16x16x32_bf16(al, bh, acc1, 0, 0, 0);
    acc2 = __builtin_amdgcn_mfma_f32_16x16x32_bf16(ah, bl, acc2, 0, 0, 0);
  }
  #pragma unroll
  for (int r = 0; r < 4; ++r)
    hp[(size_t)(t0 + q*4 + r)*16 + l16] = acc0[r] + acc1[r] + acc2[r];
}

// ---------------- gating select ----------------
__global__ __launch_bounds__(256) void gating_select_kernel(
    const float* __restrict__ hp, const float* __restrict__ noise,
    const int* __restrict__ kp,
    float* __restrict__ gates, int* __restrict__ counts, int* __restrict__ lists,
    int* __restrict__ tokmap, int* __restrict__ ncnt)
{
  __shared__ int lcnt[NEXP];
  __shared__ int lbase[NEXP];
  const int tid = threadIdx.x;
  const int t   = blockIdx.x*256 + tid;
  if (tid < NEXP) lcnt[tid] = 0;
  __syncthreads();

  float hg[16];
  #pragma unroll
  for (int i = 0; i < 4; ++i){
    const float4 v = reinterpret_cast<const float4*>(hp + (size_t)t*16)[i];
    hg[i*4+0]=v.x; hg[i*4+1]=v.y; hg[i*4+2]=v.z; hg[i*4+3]=v.w;
  }
  float h[NEXP];
  #pragma unroll
  for (int e = 0; e < NEXP; ++e){
    const float hn = hg[8+e];
    const float sp = (hn > 20.f) ? hn : log1pf(expf(hn));
    h[e] = hg[e] + noise[(size_t)t*NEXP + e] + sp;
  }

  int kk = *kp; kk = kk<1?1:(kk>NEXP?NEXP:kk);
  bool used[NEXP];
  #pragma unroll
  for (int e=0;e<NEXP;e++) used[e]=false;
  float kth = 0.f;
  for (int i=0;i<kk;i++){
    int bi=0; float bv=-3.4e38f;
    #pragma unroll
    for (int e=0;e<NEXP;e++) if (!used[e] && h[e]>bv){bv=h[e]; bi=e;}
    used[bi]=true; kth=bv;
  }
  float m=-3.4e38f;
  #pragma unroll
  for (int e=0;e<NEXP;e++) if (h[e]>=kth && h[e]>m) m=h[e];
  float p[NEXP], s=0.f;
  #pragma unroll
  for (int e=0;e<NEXP;e++){ p[e]=(h[e]>=kth)?expf(h[e]-m):0.f; s+=p[e]; }
  const float inv = 1.f/s;
  float g[NEXP];
  int lslot[NEXP];
  #pragma unroll
  for (int e=0;e<NEXP;e++){
    g[e] = p[e]*inv;
    gates[(size_t)t*NEXP + e] = g[e];
    if (g[e] > 0.f) lslot[e] = atomicAdd(&lcnt[e], 1);
  }
  __syncthreads();
  if (tid < NEXP) lbase[tid] = atomicAdd(&counts[tid], lcnt[tid]);
  __syncthreads();
  int idx = 0;
  #pragma unroll
  for (int e=0;e<NEXP;e++){
    if (g[e] > 0.f){
      const int slot = lbase[e] + lslot[e];
      lists[e*BTOK + slot] = t;
      tokmap[t*NEXP + idx] = (e << 13) | (slot & 8191);
      idx++;
    }
  }
  ncnt[t] = idx;
}

// ---------------- transpose+cast W1,W2 -> bf16 WT[e][n][k] ----------------
__global__ __launch_bounds__(256) void trans_kernel(
    const float* __restrict__ W1, const float* __restrict__ W2,
    u16* __restrict__ W1T, u16* __restrict__ W2T)
{
  __shared__ float tile[64][65];
  const int mz = blockIdx.z;
  const float* src = (mz < NEXP) ? (W1  + (size_t)mz*DDIM*DDIM) : (W2  + (size_t)(mz-NEXP)*DDIM*DDIM);
  u16*       dst = (mz < NEXP) ? (W1T + (size_t)mz*DDIM*DDIM) : (W2T + (size_t)(mz-NEXP)*DDIM*DDIM);
  const int r0 = blockIdx.x*64, c0 = blockIdx.y*64;
  const int tx = threadIdx.x & 63, ty = threadIdx.x >> 6;
  #pragma unroll
  for (int i=ty;i<64;i+=4)
    tile[i][tx] = src[(size_t)(r0+i)*DDIM + c0+tx];
  __syncthreads();
  #pragma unroll
  for (int i=ty;i<64;i+=4)
    dst[(size_t)(c0+i)*DDIM + r0+tx] = f2bf(tile[tx][i]);
}

// ---- expert FFN GEMM: 256x256xBK64, 8 waves, T3-minimum single-barrier 2-phase ----
// Recipe (m230-V0/m248-V1): issue STAGE(t+1) BEFORE compute(t); one
// __syncthreads() per K-step (its vmcnt(0)+lgkmcnt(0) drain is cheap because
// the loads had the whole compute phase to fly). No pins, no asm waits.
template<int LAYER>
__device__ __forceinline__ void ffn_body(
    const u16* __restrict__ Asrc, const u16* __restrict__ WT,
    const float* __restrict__ bias,
    const int* __restrict__ counts, const int* __restrict__ lists,
    u16* __restrict__ dst)
{
  // 1D grid: expert = wgid & 7 -> all of an expert's blocks on one XCD (L2 reuse)
  const int lin = blockIdx.x;
  const int e   = lin & 7;
  const int idx = lin >> 3;                 // 0..47
  const int m0  = (idx >> 2) * BM;          // 12 m-blocks
  const int n0  = (idx & 3)  * BN;          // 4 n-blocks
  int cnt = counts[e]; if (cnt > SLOTCAP) cnt = SLOTCAP;
  if (m0 >= cnt) return;                    // uniform early-exit (before any barrier)

  __shared__ __align__(16) u16 ldsA[2][BM*BK];   // 64 KB
  __shared__ __align__(16) u16 ldsB[2][BN*BK];   // 64 KB

  const int tid = threadIdx.x;
  const int wave = tid>>6, lane = tid&63;
  const int wm = wave>>2, wn = wave&3;           // 2M x 4N waves

  // staging sources (T2 both-sides rule: linear LDS dest, pre-swizzled global src)
  const u16* aSrc[4]; const u16* bSrc[4];
  {
    const int lr = lane>>3, sp = lane&7;
    #pragma unroll
    for (int i=0;i<4;i++){
      const int row = wave*32 + i*8 + lr;        // 0..255
      const int ku  = sp ^ (row&7);
      size_t abase;
      if constexpr (LAYER==1){
        int gr = m0 + row; if (gr >= cnt) gr = cnt-1;   // clamp: dup rows
        abase = (size_t)lists[e*BTOK + gr] * DDIM;
      } else {
        abase = ((size_t)e*SLOTCAP + m0 + row) * DDIM;
      }
      aSrc[i] = Asrc + abase + ku*8;
      bSrc[i] = WT + ((size_t)e*DDIM + n0 + row)*DDIM + ku*8;
    }
  }

  const int q = lane>>4, l16 = lane&15;
  // swizzled ds_read offsets (u16 units) for kk=0; kk=1 is ^32 (slot bit2 flip)
  int aoff[8], boff[4];
  #pragma unroll
  for (int f=0;f<8;f++){
    const int ra = wm*128 + f*16 + l16;
    aoff[f] = ra*BK + ((q ^ (ra&7))*8);
  }
  #pragma unroll
  for (int f=0;f<4;f++){
    const int rb = wn*64 + f*16 + l16;
    boff[f] = rb*BK + ((q ^ (rb&7))*8);
  }

  f32x4 acc[8][4];
  #pragma unroll
  for (int i=0;i<8;i++)
    #pragma unroll
    for (int j=0;j<4;j++)
      acc[i][j] = (f32x4){0.f,0.f,0.f,0.f};

  #define STAGE(T, c)                                            \
    _Pragma("unroll")                                            \
    for (int i=0;i<4;i++){                                       \
      gll16(aSrc[i] + (size_t)(T)*BK, &ldsA[c][(wave*32+i*8)*BK]); \
      gll16(bSrc[i] + (size_t)(T)*BK, &ldsB[c][(wave*32+i*8)*BK]); \
    }

  STAGE(0, 0)
  __syncthreads();
  int cur = 0;
  for (int kt = 0; kt < NT; ++kt){
    if (kt + 1 < NT) STAGE(kt+1, cur^1)     // issue next-tile loads FIRST
    // compute tile kt from buf cur (compiler interleaves ds_read/MFMA)
    #pragma unroll
    for (int kk=0; kk<2; kk++){
      const int kx = kk ? 32 : 0;
      short8 bfr[4], afr[8];
      #pragma unroll
      for (int f=0;f<4;f++) bfr[f] = *reinterpret_cast<const short8*>(&ldsB[cur][boff[f] ^ kx]);
      #pragma unroll
      for (int f=0;f<8;f++) afr[f] = *reinterpret_cast<const short8*>(&ldsA[cur][aoff[f] ^ kx]);
      __builtin_amdgcn_s_setprio(1);
      #pragma unroll
      for (int fm=0;fm<8;fm++)
        #pragma unroll
        for (int fn=0;fn<4;fn++)
          acc[fm][fn] = __builtin_amdgcn_mfma_f32_16x16x32_bf16(afr[fm], bfr[fn], acc[fm][fn], 0, 0, 0);
      __builtin_amdgcn_s_setprio(0);
    }
    __syncthreads();                        // vmcnt(0)+lgkm(0)+barrier: next buf ready
    cur ^= 1;
  }
  #undef STAGE

  // epilogue: C/D layout col=lane&15, row=(lane>>4)*4+reg
  #pragma unroll
  for (int fm=0;fm<8;fm++){
    #pragma unroll
    for (int r=0;r<4;r++){
      const int row = wm*128 + fm*16 + q*4 + r;
      const int gr  = m0 + row;                 // < SLOTCAP by grid
      #pragma unroll
      for (int fn=0;fn<4;fn++){
        const int col = n0 + wn*64 + fn*16 + l16;
        float v = acc[fm][fn][r] + bias[e*DDIM + col];
        if constexpr (LAYER==1) v = v > 0.f ? v : 0.f;
        dst[((size_t)e*SLOTCAP + gr)*DDIM + col] = f2bf(v);
      }
    }
  }
}

__global__ __launch_bounds__(512, 1) void ffn1_kernel(
    const u16* __restrict__ A, const u16* __restrict__ WT, const float* __restrict__ b,
    const int* __restrict__ counts, const int* __restrict__ lists, u16* __restrict__ dst)
{ ffn_body<1>(A, WT, b, counts, lists, dst); }

__global__ __launch_bounds__(512, 1) void ffn2_kernel(
    const u16* __restrict__ A, const u16* __restrict__ WT, const float* __restrict__ b,
    const int* __restrict__ counts, const int* __restrict__ lists, u16* __restrict__ dst)
{ ffn_body<2>(A, WT, b, counts, lists, dst); }

// ---------------- combine ----------------
__global__ __launch_bounds__(256) void combine_kernel(
    const u16* __restrict__ partial, const int* __restrict__ tokmap,
    const int* __restrict__ ncnt, const float* __restrict__ gates,
    float* __restrict__ out)
{
  const int t = blockIdx.x, c = threadIdx.x;
  const int n = ncnt[t];
  float4 acc = {0.f, 0.f, 0.f, 0.f};
  for (int j = 0; j < n; ++j){
    const int ent  = tokmap[t*NEXP + j];
    const int e    = ent >> 13, slot = ent & 8191;
    if (slot >= SLOTCAP) continue;
    const float g = gates[(size_t)t*NEXP + e];
    const ushort4 pv = reinterpret_cast<const ushort4*>(
        partial + ((size_t)e*SLOTCAP + slot)*DDIM)[c];
    acc.x = fmaf(g, bf2f(pv.x), acc.x);
    acc.y = fmaf(g, bf2f(pv.y), acc.y);
    acc.z = fmaf(g, bf2f(pv.z), acc.z);
    acc.w = fmaf(g, bf2f(pv.w), acc.w);
  }
  reinterpret_cast<float4*>(out + (size_t)t*DDIM)[c] = acc;
}

// ---------------- host launch ----------------
extern "C" void kernel_launch(void* const* d_in, const int* in_sizes, int n_in,
                              void* d_out, int out_size, void* d_ws, size_t ws_size,
                              hipStream_t stream)
{
  const float* x     = (const float*)d_in[0];
  const float* noise = (const float*)d_in[1];
  const float* Wg    = (const float*)d_in[2];
  const float* Wn    = (const float*)d_in[3];
  const float* W1    = (const float*)d_in[4];
  const float* b1    = (const float*)d_in[5];
  const float* W2    = (const float*)d_in[6];
  const float* b2    = (const float*)d_in[7];
  const int*   kp    = (const int*)d_in[8];
  float* out = (float*)d_out;

  char* ws = (char*)d_ws;
  int*   counts = (int*)ws;                      // 4K
  int*   lists  = (int*)(ws + 4096);             // 256K
  float* gates  = (float*)(ws + 266240);         // 256K
  int*   tokmap = (int*)(ws + 528384);           // 256K
  int*   ncnt   = (int*)(ws + 790528);           // 32K
  u16*   xb     = (u16*)(ws + 823296);           // 16.78M
  u16*   W1T    = (u16*)(ws + 17600512);         // 16.78M
  u16*   W2T    = (u16*)(ws + 34377728);         // 16.78M
  u16*   hidden = (u16*)(ws + 51154944);         // 50.33M
  u16*   partial= (u16*)(ws + 101486592);        // 50.33M
  // transient aliases inside `partial` (dead before ffn2 writes it):
  float* hp     = (float*)(ws + 101486592);      // 512K  h'[8192][16]
  u16*   wpt    = (u16*)(ws + 102010880);        // 64K   W'T hi/lo
  const size_t NEED = 151818240ull;

  hipMemsetAsync(counts, 0, 64, stream);
  if (ws_size < NEED){
    hipMemsetAsync(d_out, 0, (size_t)out_size*sizeof(float), stream);
    return;
  }

  wprep_kernel<<<64, 256, 0, stream>>>(Wg, Wn, wpt);
  trans_kernel<<<dim3(16,16,16), 256, 0, stream>>>(W1, W2, W1T, W2T);
  score_kernel<<<BTOK/32, 128, 0, stream>>>(x, wpt, hp, xb);
  gating_select_kernel<<<BTOK/256, 256, 0, stream>>>(hp, noise, kp, gates, counts, lists,
                                                     tokmap, ncnt);
  ffn1_kernel<<<(SLOTCAP/BM)*4*NEXP, 512, 0, stream>>>(
      xb, W1T, b1, counts, lists, hidden);
  ffn2_kernel<<<(SLOTCAP/BM)*4*NEXP, 512, 0, stream>>>(
      hidden, W2T, b2, counts, lists, partial);
  combine_kernel<<<BTOK, 256, 0, stream>>>(partial, tokmap, ncnt, gates, out);
}

// Round 10
// 319.359 us; speedup vs baseline: 2.3315x; 1.0146x over previous
//
#include <hip/hip_runtime.h>
#include <hip/hip_bf16.h>

#define BTOK 8192
#define DDIM 1024
#define NEXP 8

typedef unsigned short u16;
typedef unsigned int u32;
typedef __attribute__((ext_vector_type(8))) short short8;
typedef __attribute__((ext_vector_type(4))) float f32x4;

constexpr int BM = 256, BN = 256, BK = 64;
constexpr int SLOTCAP = 3072;
constexpr int NT = DDIM / BK;          // 16 K-tiles
constexpr int RBM = 64, RBN = 256;     // ragged tile

__device__ __forceinline__ u16 f2bf(float f){
  __hip_bfloat16 h = __float2bfloat16(f);
  return *reinterpret_cast<u16*>(&h);
}
__device__ __forceinline__ float bf2f(u16 v){
  return __uint_as_float(((u32)v) << 16);
}
__device__ __forceinline__ void gll16(const u16* gsrc, u16* ldst){
  __builtin_amdgcn_global_load_lds((const __attribute__((address_space(1))) void*)gsrc,
                                   (__attribute__((address_space(3))) void*)ldst,
                                   16, 0, 0);
}

// ---------------- W' prep: W'T[n][d] hi/lo bf16, n<8 = Wg col, n>=8 = Wn col ----------------
__global__ __launch_bounds__(256) void wprep_kernel(
    const float* __restrict__ Wg, const float* __restrict__ Wn,
    u16* __restrict__ wpt)
{
  const int idx = blockIdx.x*256 + threadIdx.x;     // 16384 = 16 n x 1024 d
  const int n = idx >> 10, d = idx & 1023;
  const float v = (n < 8) ? Wg[d*8 + n] : Wn[d*8 + (n-8)];
  const u16 hi = f2bf(v);
  const u16 lo = f2bf(v - bf2f(hi));
  wpt[n*1024 + d]          = hi;
  wpt[16384 + n*1024 + d]  = lo;
}

// ------- gating score: h' = x @ W' via split-bf16 MFMA; also emits xb (x as bf16) -------
__global__ __launch_bounds__(128) void score_kernel(
    const float* __restrict__ x, const u16* __restrict__ wpt,
    float* __restrict__ hp, u16* __restrict__ xb)
{
  __shared__ __align__(16) u16 lw[2][16][1024];   // 64 KB
  const int tid = threadIdx.x;
  const int wave = tid >> 6, lane = tid & 63;

  for (int it = 0; it < 32; ++it){
    const int cid = it*128 + tid;                 // 0..4095 (16B chunks)
    const int v = cid >> 11, rem = cid & 2047;
    const int n = rem >> 7, c = rem & 127;
    const short8 val = *reinterpret_cast<const short8*>(wpt + v*16384 + n*1024 + c*8);
    *reinterpret_cast<short8*>(&lw[v][n][(c ^ (n&7))*8]) = val;
  }
  __syncthreads();

  const int q = lane >> 4, l16 = lane & 15;
  const int t0 = blockIdx.x*32 + wave*16;
  const int rowA = t0 + l16;
  const float* xp  = x  + (size_t)rowA*DDIM + q*8;
  u16*         xbo = xb + (size_t)rowA*DDIM + q*8;

  f32x4 acc0 = {0.f,0.f,0.f,0.f}, acc1 = acc0, acc2 = acc0;
  for (int kt = 0; kt < 32; ++kt){
    const float4 x0 = *reinterpret_cast<const float4*>(xp + kt*32);
    const float4 x1 = *reinterpret_cast<const float4*>(xp + kt*32 + 4);
    short8 ah;
    ah[0]=(short)f2bf(x0.x); ah[1]=(short)f2bf(x0.y);
    ah[2]=(short)f2bf(x0.z); ah[3]=(short)f2bf(x0.w);
    ah[4]=(short)f2bf(x1.x); ah[5]=(short)f2bf(x1.y);
    ah[6]=(short)f2bf(x1.z); ah[7]=(short)f2bf(x1.w);
    *reinterpret_cast<short8*>(xbo + kt*32) = ah;   // fused x->bf16 cast
    short8 al;
    al[0]=(short)f2bf(x0.x - bf2f((u16)ah[0])); al[1]=(short)f2bf(x0.y - bf2f((u16)ah[1]));
    al[2]=(short)f2bf(x0.z - bf2f((u16)ah[2])); al[3]=(short)f2bf(x0.w - bf2f((u16)ah[3]));
    al[4]=(short)f2bf(x1.x - bf2f((u16)ah[4])); al[5]=(short)f2bf(x1.y - bf2f((u16)ah[5]));
    al[6]=(short)f2bf(x1.z - bf2f((u16)ah[6])); al[7]=(short)f2bf(x1.w - bf2f((u16)ah[7]));
    const int bs = ((kt*4 + q) ^ (l16 & 7)) * 8;
    const short8 bh = *reinterpret_cast<const short8*>(&lw[0][l16][bs]);
    const short8 bl = *reinterpret_cast<const short8*>(&lw[1][l16][bs]);
    acc0 = __builtin_amdgcn_mfma_f32_16x16x32_bf16(ah, bh, acc0, 0, 0, 0);
    acc1 = __builtin_amdgcn_mfma_f32_16x16x32_bf16(al, bh, acc1, 0, 0, 0);
    acc2 = __builtin_amdgcn_mfma_f32_16x16x32_bf16(ah, bl, acc2, 0, 0, 0);
  }
  #pragma unroll
  for (int r = 0; r < 4; ++r)
    hp[(size_t)(t0 + q*4 + r)*16 + l16] = acc0[r] + acc1[r] + acc2[r];
}

// ---------------- gating select ----------------
__global__ __launch_bounds__(256) void gating_select_kernel(
    const float* __restrict__ hp, const float* __restrict__ noise,
    const int* __restrict__ kp,
    float* __restrict__ gates, int* __restrict__ counts, int* __restrict__ lists,
    int* __restrict__ tokmap, int* __restrict__ ncnt)
{
  __shared__ int lcnt[NEXP];
  __shared__ int lbase[NEXP];
  const int tid = threadIdx.x;
  const int t   = blockIdx.x*256 + tid;
  if (tid < NEXP) lcnt[tid] = 0;
  __syncthreads();

  float hg[16];
  #pragma unroll
  for (int i = 0; i < 4; ++i){
    const float4 v = reinterpret_cast<const float4*>(hp + (size_t)t*16)[i];
    hg[i*4+0]=v.x; hg[i*4+1]=v.y; hg[i*4+2]=v.z; hg[i*4+3]=v.w;
  }
  float h[NEXP];
  #pragma unroll
  for (int e = 0; e < NEXP; ++e){
    const float hn = hg[8+e];
    const float sp = (hn > 20.f) ? hn : log1pf(expf(hn));
    h[e] = hg[e] + noise[(size_t)t*NEXP + e] + sp;
  }

  int kk = *kp; kk = kk<1?1:(kk>NEXP?NEXP:kk);
  bool used[NEXP];
  #pragma unroll
  for (int e=0;e<NEXP;e++) used[e]=false;
  float kth = 0.f;
  for (int i=0;i<kk;i++){
    int bi=0; float bv=-3.4e38f;
    #pragma unroll
    for (int e=0;e<NEXP;e++) if (!used[e] && h[e]>bv){bv=h[e]; bi=e;}
    used[bi]=true; kth=bv;
  }
  float m=-3.4e38f;
  #pragma unroll
  for (int e=0;e<NEXP;e++) if (h[e]>=kth && h[e]>m) m=h[e];
  float p[NEXP], s=0.f;
  #pragma unroll
  for (int e=0;e<NEXP;e++){ p[e]=(h[e]>=kth)?expf(h[e]-m):0.f; s+=p[e]; }
  const float inv = 1.f/s;
  float g[NEXP];
  int lslot[NEXP];
  #pragma unroll
  for (int e=0;e<NEXP;e++){
    g[e] = p[e]*inv;
    gates[(size_t)t*NEXP + e] = g[e];
    if (g[e] > 0.f) lslot[e] = atomicAdd(&lcnt[e], 1);
  }
  __syncthreads();
  if (tid < NEXP) lbase[tid] = atomicAdd(&counts[tid], lcnt[tid]);
  __syncthreads();
  int idx = 0;
  #pragma unroll
  for (int e=0;e<NEXP;e++){
    if (g[e] > 0.f){
      const int slot = lbase[e] + lslot[e];
      lists[e*BTOK + slot] = t;
      tokmap[t*NEXP + idx] = (e << 13) | (slot & 8191);
      idx++;
    }
  }
  ncnt[t] = idx;
}

// ---------------- transpose+cast W1,W2 -> bf16 WT[e][n][k] ----------------
__global__ __launch_bounds__(256) void trans_kernel(
    const float* __restrict__ W1, const float* __restrict__ W2,
    u16* __restrict__ W1T, u16* __restrict__ W2T)
{
  __shared__ float tile[64][65];
  const int mz = blockIdx.z;
  const float* src = (mz < NEXP) ? (W1  + (size_t)mz*DDIM*DDIM) : (W2  + (size_t)(mz-NEXP)*DDIM*DDIM);
  u16*       dst = (mz < NEXP) ? (W1T + (size_t)mz*DDIM*DDIM) : (W2T + (size_t)(mz-NEXP)*DDIM*DDIM);
  const int r0 = blockIdx.x*64, c0 = blockIdx.y*64;
  const int tx = threadIdx.x & 63, ty = threadIdx.x >> 6;
  #pragma unroll
  for (int i=ty;i<64;i+=4)
    tile[i][tx] = src[(size_t)(r0+i)*DDIM + c0+tx];
  __syncthreads();
  #pragma unroll
  for (int i=ty;i<64;i+=4)
    dst[(size_t)(c0+i)*DDIM + r0+tx] = f2bf(tile[tx][i]);
}

// ---- expert FFN GEMM: 256x256xBK64, 8 waves, T3-minimum 2-phase, FULL TILES ONLY ----
// Grid fix (R9 post-mortem): only m0+BM <= cnt blocks run -> <=32 active/XCD
// with e=wgid&7 pinning -> exactly 1 round. Remainder rows go to ragged kernel.
template<int LAYER>
__device__ __forceinline__ void ffn_body(
    const u16* __restrict__ Asrc, const u16* __restrict__ WT,
    const float* __restrict__ bias,
    const int* __restrict__ counts, const int* __restrict__ lists,
    u16* __restrict__ dst)
{
  const int lin = blockIdx.x;
  const int e   = lin & 7;
  const int idx = lin >> 3;                 // 0..47
  const int m0  = (idx >> 2) * BM;          // 12 m-slots
  const int n0  = (idx & 3)  * BN;          // 4 n-blocks
  int cnt = counts[e]; if (cnt > SLOTCAP) cnt = SLOTCAP;
  if (m0 + BM > cnt) return;                // FULL tiles only (uniform, pre-barrier)

  __shared__ __align__(16) u16 ldsA[2][BM*BK];   // 64 KB
  __shared__ __align__(16) u16 ldsB[2][BN*BK];   // 64 KB

  const int tid = threadIdx.x;
  const int wave = tid>>6, lane = tid&63;
  const int wm = wave>>2, wn = wave&3;           // 2M x 4N waves

  // staging sources (T2 both-sides rule: linear LDS dest, pre-swizzled global src)
  const u16* aSrc[4]; const u16* bSrc[4];
  {
    const int lr = lane>>3, sp = lane&7;
    #pragma unroll
    for (int i=0;i<4;i++){
      const int row = wave*32 + i*8 + lr;        // 0..255
      const int ku  = sp ^ (row&7);
      size_t abase;
      if constexpr (LAYER==1){
        abase = (size_t)lists[e*BTOK + m0 + row] * DDIM;   // full tile: row valid
      } else {
        abase = ((size_t)e*SLOTCAP + m0 + row) * DDIM;
      }
      aSrc[i] = Asrc + abase + ku*8;
      bSrc[i] = WT + ((size_t)e*DDIM + n0 + row)*DDIM + ku*8;
    }
  }

  const int q = lane>>4, l16 = lane&15;
  // swizzled ds_read offsets (u16 units) for kk=0; kk=1 is ^32 (slot bit2 flip)
  int aoff[8], boff[4];
  #pragma unroll
  for (int f=0;f<8;f++){
    const int ra = wm*128 + f*16 + l16;
    aoff[f] = ra*BK + ((q ^ (ra&7))*8);
  }
  #pragma unroll
  for (int f=0;f<4;f++){
    const int rb = wn*64 + f*16 + l16;
    boff[f] = rb*BK + ((q ^ (rb&7))*8);
  }

  f32x4 acc[8][4];
  #pragma unroll
  for (int i=0;i<8;i++)
    #pragma unroll
    for (int j=0;j<4;j++)
      acc[i][j] = (f32x4){0.f,0.f,0.f,0.f};

  #define STAGE(T, c)                                            \
    _Pragma("unroll")                                            \
    for (int i=0;i<4;i++){                                       \
      gll16(aSrc[i] + (size_t)(T)*BK, &ldsA[c][(wave*32+i*8)*BK]); \
      gll16(bSrc[i] + (size_t)(T)*BK, &ldsB[c][(wave*32+i*8)*BK]); \
    }

  STAGE(0, 0)
  __syncthreads();
  int cur = 0;
  for (int kt = 0; kt < NT; ++kt){
    if (kt + 1 < NT) STAGE(kt+1, cur^1)     // issue next-tile loads FIRST
    #pragma unroll
    for (int kk=0; kk<2; kk++){
      const int kx = kk ? 32 : 0;
      short8 bfr[4], afr[8];
      #pragma unroll
      for (int f=0;f<4;f++) bfr[f] = *reinterpret_cast<const short8*>(&ldsB[cur][boff[f] ^ kx]);
      #pragma unroll
      for (int f=0;f<8;f++) afr[f] = *reinterpret_cast<const short8*>(&ldsA[cur][aoff[f] ^ kx]);
      __builtin_amdgcn_s_setprio(1);
      #pragma unroll
      for (int fm=0;fm<8;fm++)
        #pragma unroll
        for (int fn=0;fn<4;fn++)
          acc[fm][fn] = __builtin_amdgcn_mfma_f32_16x16x32_bf16(afr[fm], bfr[fn], acc[fm][fn], 0, 0, 0);
      __builtin_amdgcn_s_setprio(0);
    }
    __syncthreads();                        // next buf ready, reads done
    cur ^= 1;
  }
  #undef STAGE

  // epilogue: C/D layout col=lane&15, row=(lane>>4)*4+reg
  #pragma unroll
  for (int fm=0;fm<8;fm++){
    #pragma unroll
    for (int r=0;r<4;r++){
      const int row = wm*128 + fm*16 + q*4 + r;
      const int gr  = m0 + row;
      #pragma unroll
      for (int fn=0;fn<4;fn++){
        const int col = n0 + wn*64 + fn*16 + l16;
        float v = acc[fm][fn][r] + bias[e*DDIM + col];
        if constexpr (LAYER==1) v = v > 0.f ? v : 0.f;
        dst[((size_t)e*SLOTCAP + gr)*DDIM + col] = f2bf(v);
      }
    }
  }
}

__global__ __launch_bounds__(512, 1) void ffn1_kernel(
    const u16* __restrict__ A, const u16* __restrict__ WT, const float* __restrict__ b,
    const int* __restrict__ counts, const int* __restrict__ lists, u16* __restrict__ dst)
{ ffn_body<1>(A, WT, b, counts, lists, dst); }

__global__ __launch_bounds__(512, 1) void ffn2_kernel(
    const u16* __restrict__ A, const u16* __restrict__ WT, const float* __restrict__ b,
    const int* __restrict__ counts, const int* __restrict__ lists, u16* __restrict__ dst)
{ ffn_body<2>(A, WT, b, counts, lists, dst); }

// ---- ragged tail: rows [floor(cnt/256)*256, cnt), 64x256 tiles, 4 waves ----
template<int LAYER>
__device__ __forceinline__ void ragged_body(
    const u16* __restrict__ Asrc, const u16* __restrict__ WT,
    const float* __restrict__ bias,
    const int* __restrict__ counts, const int* __restrict__ lists,
    u16* __restrict__ dst)
{
  const int lin = blockIdx.x;
  const int e   = lin & 7;
  const int r2  = lin >> 3;                 // 0..15
  const int rs  = r2 >> 2;                  // 0..3 (64-row sub-tile)
  const int nt  = r2 & 3;                   // 0..3
  int cnt = counts[e]; if (cnt > SLOTCAP) cnt = SLOTCAP;
  const int base = (cnt >> 8) << 8;         // floor(cnt/256)*256
  const int m0 = base + rs*RBM;
  if (m0 >= cnt) return;                    // uniform, pre-barrier
  const int n0 = nt * RBN;

  __shared__ __align__(16) u16 ldsA[2][RBM*BK];  // 16 KB
  __shared__ __align__(16) u16 ldsB[2][RBN*BK];  // 64 KB

  const int tid = threadIdx.x;
  const int wave = tid>>6, lane = tid&63;   // 4 waves; wave = wn (col split)
  const int lr = lane>>3, sp = lane&7;

  const u16* aSrc[2]; const u16* bSrc[8];
  #pragma unroll
  for (int i=0;i<2;i++){
    const int row = wave*16 + i*8 + lr;     // 0..63
    const int ku  = sp ^ (row&7);
    int gr = m0 + row; if (gr >= cnt) gr = cnt-1;   // clamp: dup rows, store-guarded
    size_t abase;
    if constexpr (LAYER==1) abase = (size_t)lists[e*BTOK + gr] * DDIM;
    else                    abase = ((size_t)e*SLOTCAP + gr) * DDIM;
    aSrc[i] = Asrc + abase + ku*8;
  }
  #pragma unroll
  for (int i=0;i<8;i++){
    const int row = wave*64 + i*8 + lr;     // 0..255 (B rows = output cols)
    const int ku  = sp ^ (row&7);
    bSrc[i] = WT + ((size_t)e*DDIM + n0 + row)*DDIM + ku*8;
  }

  const int q = lane>>4, l16 = lane&15;
  int aoff[4], boff[4];
  #pragma unroll
  for (int f=0;f<4;f++){
    const int ra = f*16 + l16;              // 0..63
    aoff[f] = ra*BK + ((q ^ (ra&7))*8);
    const int rb = wave*64 + f*16 + l16;    // 0..255
    boff[f] = rb*BK + ((q ^ (rb&7))*8);
  }

  f32x4 acc[4][4];
  #pragma unroll
  for (int i=0;i<4;i++)
    #pragma unroll
    for (int j=0;j<4;j++)
      acc[i][j] = (f32x4){0.f,0.f,0.f,0.f};

  #define RSTAGE(T, c)                                             \
    _Pragma("unroll")                                              \
    for (int i=0;i<2;i++)                                          \
      gll16(aSrc[i] + (size_t)(T)*BK, &ldsA[c][(wave*16+i*8)*BK]); \
    _Pragma("unroll")                                              \
    for (int i=0;i<8;i++)                                          \
      gll16(bSrc[i] + (size_t)(T)*BK, &ldsB[c][(wave*64+i*8)*BK]);

  RSTAGE(0, 0)
  __syncthreads();
  int cur = 0;
  for (int kt = 0; kt < NT; ++kt){
    if (kt + 1 < NT) { RSTAGE(kt+1, cur^1) }
    #pragma unroll
    for (int kk=0; kk<2; kk++){
      const int kx = kk ? 32 : 0;
      short8 afr[4], bfr[4];
      #pragma unroll
      for (int f=0;f<4;f++) afr[f] = *reinterpret_cast<const short8*>(&ldsA[cur][aoff[f] ^ kx]);
      #pragma unroll
      for (int f=0;f<4;f++) bfr[f] = *reinterpret_cast<const short8*>(&ldsB[cur][boff[f] ^ kx]);
      #pragma unroll
      for (int fm=0;fm<4;fm++)
        #pragma unroll
        for (int fn=0;fn<4;fn++)
          acc[fm][fn] = __builtin_amdgcn_mfma_f32_16x16x32_bf16(afr[fm], bfr[fn], acc[fm][fn], 0, 0, 0);
    }
    __syncthreads();
    cur ^= 1;
  }
  #undef RSTAGE

  #pragma unroll
  for (int fm=0;fm<4;fm++){
    #pragma unroll
    for (int r=0;r<4;r++){
      const int row = fm*16 + q*4 + r;
      const int gr  = m0 + row;
      if (gr < cnt){
        #pragma unroll
        for (int fn=0;fn<4;fn++){
          const int col = n0 + wave*64 + fn*16 + l16;
          float v = acc[fm][fn][r] + bias[e*DDIM + col];
          if constexpr (LAYER==1) v = v > 0.f ? v : 0.f;
          dst[((size_t)e*SLOTCAP + gr)*DDIM + col] = f2bf(v);
        }
      }
    }
  }
}

__global__ __launch_bounds__(256, 1) void ragged1_kernel(
    const u16* __restrict__ A, const u16* __restrict__ WT, const float* __restrict__ b,
    const int* __restrict__ counts, const int* __restrict__ lists, u16* __restrict__ dst)
{ ragged_body<1>(A, WT, b, counts, lists, dst); }

__global__ __launch_bounds__(256, 1) void ragged2_kernel(
    const u16* __restrict__ A, const u16* __restrict__ WT, const float* __restrict__ b,
    const int* __restrict__ counts, const int* __restrict__ lists, u16* __restrict__ dst)
{ ragged_body<2>(A, WT, b, counts, lists, dst); }

// ---------------- combine ----------------
__global__ __launch_bounds__(256) void combine_kernel(
    const u16* __restrict__ partial, const int* __restrict__ tokmap,
    const int* __restrict__ ncnt, const float* __restrict__ gates,
    float* __restrict__ out)
{
  const int t = blockIdx.x, c = threadIdx.x;
  const int n = ncnt[t];
  float4 acc = {0.f, 0.f, 0.f, 0.f};
  for (int j = 0; j < n; ++j){
    const int ent  = tokmap[t*NEXP + j];
    const int e    = ent >> 13, slot = ent & 8191;
    if (slot >= SLOTCAP) continue;
    const float g = gates[(size_t)t*NEXP + e];
    const ushort4 pv = reinterpret_cast<const ushort4*>(
        partial + ((size_t)e*SLOTCAP + slot)*DDIM)[c];
    acc.x = fmaf(g, bf2f(pv.x), acc.x);
    acc.y = fmaf(g, bf2f(pv.y), acc.y);
    acc.z = fmaf(g, bf2f(pv.z), acc.z);
    acc.w = fmaf(g, bf2f(pv.w), acc.w);
  }
  reinterpret_cast<float4*>(out + (size_t)t*DDIM)[c] = acc;
}

// ---------------- host launch ----------------
extern "C" void kernel_launch(void* const* d_in, const int* in_sizes, int n_in,
                              void* d_out, int out_size, void* d_ws, size_t ws_size,
                              hipStream_t stream)
{
  const float* x     = (const float*)d_in[0];
  const float* noise = (const float*)d_in[1];
  const float* Wg    = (const float*)d_in[2];
  const float* Wn    = (const float*)d_in[3];
  const float* W1    = (const float*)d_in[4];
  const float* b1    = (const float*)d_in[5];
  const float* W2    = (const float*)d_in[6];
  const float* b2    = (const float*)d_in[7];
  const int*   kp    = (const int*)d_in[8];
  float* out = (float*)d_out;

  char* ws = (char*)d_ws;
  int*   counts = (int*)ws;                      // 4K
  int*   lists  = (int*)(ws + 4096);             // 256K
  float* gates  = (float*)(ws + 266240);         // 256K
  int*   tokmap = (int*)(ws + 528384);           // 256K
  int*   ncnt   = (int*)(ws + 790528);           // 32K
  u16*   xb     = (u16*)(ws + 823296);           // 16.78M
  u16*   W1T    = (u16*)(ws + 17600512);         // 16.78M
  u16*   W2T    = (u16*)(ws + 34377728);         // 16.78M
  u16*   hidden = (u16*)(ws + 51154944);         // 50.33M
  u16*   partial= (u16*)(ws + 101486592);        // 50.33M
  // transient aliases inside `partial` (dead before ffn2/ragged2 write it):
  float* hp     = (float*)(ws + 101486592);      // 512K  h'[8192][16]
  u16*   wpt    = (u16*)(ws + 102010880);        // 64K   W'T hi/lo
  const size_t NEED = 151818240ull;

  hipMemsetAsync(counts, 0, 64, stream);
  if (ws_size < NEED){
    hipMemsetAsync(d_out, 0, (size_t)out_size*sizeof(float), stream);
    return;
  }

  wprep_kernel<<<64, 256, 0, stream>>>(Wg, Wn, wpt);
  trans_kernel<<<dim3(16,16,16), 256, 0, stream>>>(W1, W2, W1T, W2T);
  score_kernel<<<BTOK/32, 128, 0, stream>>>(x, wpt, hp, xb);
  gating_select_kernel<<<BTOK/256, 256, 0, stream>>>(hp, noise, kp, gates, counts, lists,
                                                     tokmap, ncnt);
  ffn1_kernel<<<(SLOTCAP/BM)*4*NEXP, 512, 0, stream>>>(
      xb, W1T, b1, counts, lists, hidden);
  ragged1_kernel<<<128, 256, 0, stream>>>(
      xb, W1T, b1, counts, lists, hidden);
  ffn2_kernel<<<(SLOTCAP/BM)*4*NEXP, 512, 0, stream>>>(
      hidden, W2T, b2, counts, lists, partial);
  ragged2_kernel<<<128, 256, 0, stream>>>(
      hidden, W2T, b2, counts, lists, partial);
  combine_kernel<<<BTOK, 256, 0, stream>>>(partial, tokmap, ncnt, gates, out);
}